// Round 5
// baseline (10138.754 us; speedup 1.0000x reference)
//
#include <hip/hip_runtime.h>
#include <hip/hip_bf16.h>

#define H_DIM 1024
#define B_DIM 64
#define T_DIM 512
#define I_PAD 128
#define I_ORIG 118
#define FC_DIM 16
#define HB (B_DIM * H_DIM)
#define EX_SLOT 65536   // dwords per tagged exchange slot (64 rows x 1024)

typedef __hip_bfloat16 bf16;
typedef __attribute__((ext_vector_type(8))) short short8v;
typedef __attribute__((ext_vector_type(4))) float f32x4;

#define MFMA16(a, b, c) __builtin_amdgcn_mfma_f32_16x16x32_bf16(a, b, c, 0, 0, 0)

__device__ __forceinline__ short8v ldg8(const bf16* p) {
    return *reinterpret_cast<const short8v*>(p);
}
__device__ __forceinline__ unsigned short f2bf_bits(float f) {
    union { bf16 h; unsigned short s; } u;
    u.h = __float2bfloat16(f);
    return u.s;
}
__device__ __forceinline__ unsigned ld_coh(const unsigned* p) {
    return __hip_atomic_load(p, __ATOMIC_RELAXED, __HIP_MEMORY_SCOPE_AGENT);
}
__device__ __forceinline__ void st_coh(unsigned* p, unsigned v) {
    __hip_atomic_store(p, v, __ATOMIC_RELAXED, __HIP_MEMORY_SCOPE_AGENT);
}

// ---------------------------------------------------------------------------
// x[b][t][i] f32 -> x_bf[t][b][c] bf16 (c padded 118->128 with zeros)
// ---------------------------------------------------------------------------
__global__ __launch_bounds__(256) void cvt_x_kernel(
    const float* __restrict__ x, bf16* __restrict__ out)
{
    int idx  = blockIdx.x * 256 + threadIdx.x;
    int c    = idx & 127;
    int rest = idx >> 7;
    int b    = rest & 63;
    int t    = rest >> 6;
    float v  = (c < I_ORIG) ? x[((long)b * T_DIM + t) * I_ORIG + c] : 0.0f;
    out[idx] = __float2bfloat16(v);
}

__global__ __launch_bounds__(256) void cvt_pad(
    const float* __restrict__ in, bf16* __restrict__ out,
    int kin, int kp, long total)
{
    long idx = (long)blockIdx.x * 256 + threadIdx.x;
    if (idx >= total) return;
    int  c = (int)(idx % kp);
    long r = idx / kp;
    out[idx] = __float2bfloat16(c < kin ? in[r * kin + c] : 0.0f);
}

// ---------------------------------------------------------------------------
// Persistent GRU pass. grid 256 x 256 (4 waves).
// bn = bid&63 (j-tile of 16), grp = bid>>6 (batch tile of 16 rows).
// TAGGED: recurrent exchange = dwords (tag<<16 | bf16), 2-slot ping-pong.
//   Consumer at iter t expects tag t in slot t&1; producer stores tag t+1
//   into slot (t+1)&1 AFTER the block barrier (overwrite-safety: the
//   pre-barrier verify of all 4 waves covers all 64 group blocks, so every
//   group block has finished reading tag t-1 before any tag t+1 store).
//   Hint flags (per grp,bn,wave) reduce bulk-reload traffic; tags are the
//   only correctness mechanism. One __syncthreads per step (sm_red dbuf).
// !TAGGED: single-step decoder mode; plain bf16 archive in, f32 init h.
// ---------------------------------------------------------------------------
template<int WXK, bool WXG, bool TAGGED>
__global__ __launch_bounds__(256, 1) void gru_pass(
    const bf16* __restrict__ xbase, long xstride,
    const bf16* __restrict__ WxG,   // [3*1024][WXK] (staged to LDS if !WXG)
    const bf16* __restrict__ WhG,   // [3*1024][1024]
    const float* __restrict__ bih, const float* __restrict__ bhh,
    unsigned* exbuf,                // TAGGED: 2*EX_SLOT dwords
    const bf16* hin_plain,          // !TAGGED: bf16 archive in
    bf16* h_arch, int arch_mod,     // optional bf16 archive out, slot = t%arch_mod
    const float* f_init, float* f_final,
    int nsteps, unsigned* flags)
{
    extern __shared__ char smem[];
    constexpr int WH_BYTES = 3 * 16 * 1024 * 2;                  // 98304
    constexpr int WX_BYTES = WXG ? 0 : 3 * 16 * WXK * 2;
    float* sm_red = (float*)(smem + WH_BYTES + WX_BYTES);       // 2 x 4608 words

    const int tid  = threadIdx.x;
    const int w    = tid >> 6;
    const int lane = tid & 63;
    const int ln   = lane & 15;
    const int lk   = lane >> 4;
    const int bid  = blockIdx.x;
    const int bn   = bid & 63;
    const int grp  = bid >> 6;
    const int j0   = bn * 16;
    const int m0   = grp * 16;
    const int j    = j0 + ln;

    // ---- stage Whh into LDS (swizzled), rows of 2048B
    for (int c = tid; c < WH_BYTES / 16; c += 256) {
        int lin = c * 16;
        int row = lin >> 11;
        int wb  = lin & 2047;
        int g   = row >> 4, jj = row & 15;
        const bf16* src = WhG + ((long)(g * 1024 + j0 + jj) << 10) + (wb >> 1);
        *reinterpret_cast<short8v*>(smem + (lin ^ ((jj & 7) << 4))) = ldg8(src);
    }
    if constexpr (!WXG) {
        for (int c = tid; c < WX_BYTES / 16; c += 256) {
            int lin = c * 16;
            int row = lin / (WXK * 2);
            int wb  = lin % (WXK * 2);
            int g   = row >> 4, jj = row & 15;
            const bf16* src = WxG + (long)(g * 1024 + j0 + jj) * WXK + (wb >> 1);
            *reinterpret_cast<short8v*>(smem + WH_BYTES + (lin ^ ((jj & 7) << 4))) = ldg8(src);
        }
    }
    __syncthreads();

    const int wkoh = w << 8;
    const int wkox = (WXK == 128) ? (w << 5) : (w << 8);
    const int swz  = (ln & 7) << 4;
    const int whb0 = ln * 2048 + ((wkoh + lk * 8) << 1);

    const float bias_r  = bih[j] + bhh[j];
    const float bias_z  = bih[j + H_DIM] + bhh[j + H_DIM];
    const float bias_ni = bih[j + 2 * H_DIM];
    const float bias_nh = bhh[j + 2 * H_DIM];

    const int  crow = (w << 2) | lk;          // lane's output row offset
    const int  gm   = m0 + crow;
    const long opos = (long)gm * H_DIM + j;

    float hprev = f_init ? f_init[opos] : 0.0f;

    constexpr int NKX = (WXK == 128) ? 1 : 8;
    short8v xcur[NKX];
    {
        const bf16* xr = xbase + (long)(m0 + ln) * WXK + wkox + lk * 8;
#pragma unroll
        for (int ks = 0; ks < NKX; ++ks) xcur[ks] = ldg8(xr + ks * 32);
    }

    for (int t = 0; t < nsteps; ++t) {
        f32x4 aR{0,0,0,0}, aZ{0,0,0,0}, aNI{0,0,0,0}, aNH{0,0,0,0};

        // ---- input-side gates (independent of h(t-1)) — before the poll
        if constexpr (WXK == 128) {
            int o = WH_BYTES + ln * 256 + ((wkox + lk * 8) << 1);
            short8v br  = *(const short8v*)(smem + ((o       ) ^ swz));
            short8v bz  = *(const short8v*)(smem + ((o + 4096) ^ swz));
            short8v bnn = *(const short8v*)(smem + ((o + 8192) ^ swz));
            aR  = MFMA16(xcur[0], br,  aR);
            aZ  = MFMA16(xcur[0], bz,  aZ);
            aNI = MFMA16(xcur[0], bnn, aNI);
        } else {
            const bf16* wxr = WxG + (long)(j0 + ln) * 1024 + wkox + lk * 8;
#pragma unroll
            for (int ks = 0; ks < 8; ++ks) {
                short8v br  = ldg8(wxr + ks * 32);
                short8v bz  = ldg8(wxr + (1 << 20) + ks * 32);
                short8v bnn = ldg8(wxr + (2 << 20) + ks * 32);
                aR  = MFMA16(xcur[ks], br,  aR);
                aZ  = MFMA16(xcur[ks], bz,  aZ);
                aNI = MFMA16(xcur[ks], bnn, aNI);
            }
        }

        // ---- hidden-side A fragments
        short8v ah[8];
        if constexpr (TAGGED) {
            // cheap hint poll: 64B of flags per wave, throttled
            if (t > 0) {
                const unsigned* fp = flags + (grp << 8) + (w << 6) + lane;
                const unsigned tgt = (unsigned)t;
                while (true) {
                    unsigned fv = ld_coh(fp);
                    if (__all((int)(fv >= tgt))) break;
                    __builtin_amdgcn_s_sleep(2);
                }
            }
            // bulk tagged load + verify (authoritative), retry until fresh
            const unsigned* exin = exbuf + (t & 1) * EX_SLOT
                                   + ((m0 + ln) << 10) + wkoh + lk * 8;
            const unsigned target = (unsigned)t << 16;
            while (true) {
                unsigned bad = 0;
#pragma unroll
                for (int ks = 0; ks < 8; ++ks) {
                    unsigned d[8];
#pragma unroll
                    for (int i = 0; i < 8; ++i)
                        d[i] = ld_coh(exin + ks * 32 + i);
#pragma unroll
                    for (int i = 0; i < 8; ++i) bad |= (d[i] ^ target);
                    union { unsigned u[4]; short8v v; } pk;
#pragma unroll
                    for (int i = 0; i < 4; ++i)
                        pk.u[i] = (d[2 * i] & 0xFFFFu) | (d[2 * i + 1] << 16);
                    ah[ks] = pk.v;
                }
                if (__all((int)((bad & 0xFFFF0000u) == 0u))) break;
                __builtin_amdgcn_s_sleep(2);
            }
        } else {
            const bf16* ha = hin_plain + (long)(m0 + ln) * H_DIM + wkoh + lk * 8;
#pragma unroll
            for (int ks = 0; ks < 8; ++ks) ah[ks] = ldg8(ha + ks * 32);
        }

        // prefetch next step's x fragments (off the critical path)
        short8v xnext[NKX];
        if (t + 1 < nsteps) {
            const bf16* xr = xbase + (long)(t + 1) * xstride
                             + (long)(m0 + ln) * WXK + wkox + lk * 8;
#pragma unroll
            for (int ks = 0; ks < NKX; ++ks) xnext[ks] = ldg8(xr + ks * 32);
        }

        // ---- hidden-side MFMA (Whh from LDS)
#pragma unroll
        for (int ks = 0; ks < 8; ++ks) {
            int o = whb0 + ks * 64;
            short8v br  = *(const short8v*)(smem + ((o        ) ^ swz));
            short8v bz  = *(const short8v*)(smem + ((o + 32768) ^ swz));
            short8v bnn = *(const short8v*)(smem + ((o + 65536) ^ swz));
            aR  = MFMA16(ah[ks], br,  aR);
            aZ  = MFMA16(ah[ks], bz,  aZ);
            aNH = MFMA16(ah[ks], bnn, aNH);
        }

        // ---- K-split partials to LDS (18-word padded rows, double-buffered)
        float* red = sm_red + (t & 1) * 4608;
#pragma unroll
        for (int a = 0; a < 4; ++a) {
            f32x4 v = (a == 0) ? aR : (a == 1) ? aZ : (a == 2) ? aNI : aNH;
            int base = ((w << 2) + a) * 288 + (lk * 4) * 18 + ln;
#pragma unroll
            for (int e = 0; e < 4; ++e)
                red[base + e * 18] = v[e];
        }
        __syncthreads();   // the ONLY per-step barrier (joins verify of all waves)

        // ---- reduce across waves + combine (lane owns (gm, j))
        float sR = 0, sZ = 0, sNI = 0, sNH = 0;
#pragma unroll
        for (int w2 = 0; w2 < 4; ++w2) {
            int tb = (w2 << 2) * 288 + crow * 18 + ln;
            sR  += red[tb];
            sZ  += red[tb + 288];
            sNI += red[tb + 576];
            sNH += red[tb + 864];
        }
        float rr = 1.0f / (1.0f + __expf(-(sR + bias_r)));
        float zz = 1.0f / (1.0f + __expf(-(sZ + bias_z)));
        float xn = (sNI + bias_ni) + rr * (sNH + bias_nh);
        float nn = 2.0f / (1.0f + __expf(-2.0f * xn)) - 1.0f;
        float hv = (1.0f - zz) * nn + zz * hprev;
        hprev = hv;                                   // register-carried master

        // ---- tagged exchange store (fire-and-forget; after the barrier)
        if constexpr (TAGGED) {
            st_coh(exbuf + ((t + 1) & 1) * EX_SLOT + ((long)gm << 10) + j,
                   ((unsigned)(t + 1) << 16) | (unsigned)f2bf_bits(hv));
        }
        // ---- optional plain bf16 archive (pair-packed)
        if (h_arch) {
            float ho = __shfl_xor(hv, 1);
            if ((ln & 1) == 0) {
                unsigned pk2 = (unsigned)f2bf_bits(hv)
                             | ((unsigned)f2bf_bits(ho) << 16);
                bf16* ao = h_arch + (long)(t % arch_mod) * HB;
                *(unsigned*)(ao + (opos & ~1L)) = pk2;
            }
        }
        if (t == nsteps - 1 && f_final) f_final[opos] = hv;

        // ---- hint flag (per grp,bn,wave); no drain, tags are authoritative
        if constexpr (TAGGED) {
            if (lane == 0)
                st_coh(flags + (grp << 8) + (bn << 2) + w, (unsigned)(t + 1));
        }

        if (t + 1 < nsteps) {
#pragma unroll
            for (int ks = 0; ks < NKX; ++ks) xcur[ks] = xnext[ks];
        }
    }
}

// ---------------------------------------------------------------------------
__global__ __launch_bounds__(1024) void head_kernel(
    const float* __restrict__ h2,
    const float* __restrict__ fc_W, const float* __restrict__ fc_b,
    const float* __restrict__ out_W, const float* __restrict__ out_b,
    float* __restrict__ y)
{
    __shared__ float acc_s[FC_DIM][B_DIM];
    const int b = threadIdx.x & 63;
    const int f = threadIdx.x >> 6;
    const float* wp = fc_W + (long)f * H_DIM;
    const float* hp = h2 + (long)b * H_DIM;
    float a = fc_b[f];
#pragma unroll 8
    for (int k = 0; k < H_DIM; ++k)
        a = fmaf(hp[k], wp[k], a);
    a = fmaxf(a, 0.0f);
    acc_s[f][b] = a * out_W[f];
    __syncthreads();
    if (threadIdx.x < 64) {
        float s = out_b[0];
#pragma unroll
        for (int f2 = 0; f2 < FC_DIM; ++f2) s += acc_s[f2][b];
        y[b] = s;
    }
}

// ---------------------------------------------------------------------------
extern "C" void kernel_launch(void* const* d_in, const int* in_sizes, int n_in,
                              void* d_out, int out_size, void* d_ws, size_t ws_size,
                              hipStream_t stream)
{
    const float* x      = (const float*)d_in[0];
    const float* e_Wih0 = (const float*)d_in[1];
    const float* e_Whh0 = (const float*)d_in[2];
    const float* e_bih0 = (const float*)d_in[3];
    const float* e_bhh0 = (const float*)d_in[4];
    const float* e_Wih1 = (const float*)d_in[5];
    const float* e_Whh1 = (const float*)d_in[6];
    const float* e_bih1 = (const float*)d_in[7];
    const float* e_bhh1 = (const float*)d_in[8];
    const float* d_Wih0 = (const float*)d_in[9];
    const float* d_Whh0 = (const float*)d_in[10];
    const float* d_bih0 = (const float*)d_in[11];
    const float* d_bhh0 = (const float*)d_in[12];
    const float* d_Wih1 = (const float*)d_in[13];
    const float* d_Whh1 = (const float*)d_in[14];
    const float* d_bih1 = (const float*)d_in[15];
    const float* d_bhh1 = (const float*)d_in[16];
    const float* fc_W   = (const float*)d_in[17];
    const float* fc_b   = (const float*)d_in[18];
    const float* out_W  = (const float*)d_in[19];
    const float* out_b  = (const float*)d_in[20];
    (void)in_sizes; (void)n_in; (void)out_size; (void)ws_size;

    char* p = (char*)d_ws;
    auto alloc = [&](size_t bytes) -> char* {
        char* r = p; p += (bytes + 255) & ~(size_t)255; return r;
    };
    bf16*  x_bf  = (bf16*)alloc((size_t)T_DIM * B_DIM * I_PAD * 2);
    bf16*  wih0e = (bf16*)alloc(3072ull * 128 * 2);
    bf16*  whh0e = (bf16*)alloc(3072ull * 1024 * 2);
    bf16*  wih1e = (bf16*)alloc(3072ull * 1024 * 2);
    bf16*  whh1e = (bf16*)alloc(3072ull * 1024 * 2);
    bf16*  wih0d = (bf16*)alloc(3072ull * 128 * 2);
    bf16*  whh0d = (bf16*)alloc(3072ull * 1024 * 2);
    bf16*  wih1d = (bf16*)alloc(3072ull * 1024 * 2);
    bf16*  whh1d = (bf16*)alloc(3072ull * 1024 * 2);
    bf16*  h1all = (bf16*)alloc(513ull * HB * 2);   // slot s = h1 after s steps
    bf16*  h2arc = (bf16*)alloc(2ull * HB * 2);     // h2 archive ring (mod 2)
    bf16*  hd1b  = (bf16*)alloc((size_t)HB * 2);
    unsigned* ex1 = (unsigned*)alloc(2ull * EX_SLOT * 4);
    unsigned* ex2 = (unsigned*)alloc(2ull * EX_SLOT * 4);
    float* hf1f  = (float*)alloc((size_t)HB * 4);   // pass-1 final f32 h
    float* hf2f  = (float*)alloc((size_t)HB * 4);   // pass-2 final f32 h
    float* hd1f  = (float*)alloc((size_t)HB * 4);
    float* hd2f  = (float*)alloc((size_t)HB * 4);
    unsigned* fl1 = (unsigned*)alloc(4096);         // 4 grp x 64 bn x 4 w
    unsigned* fl2 = (unsigned*)alloc(4096);

    constexpr int RED = 2 * 4608 * 4;               // 36864
    constexpr int S1  = 98304 + 12288 + RED;        // 147456
    constexpr int S2  = 98304 + RED;                // 135168
    (void)hipFuncSetAttribute((const void*)gru_pass<128, false, true>,
                              hipFuncAttributeMaxDynamicSharedMemorySize, S1);
    (void)hipFuncSetAttribute((const void*)gru_pass<1024, true, true>,
                              hipFuncAttributeMaxDynamicSharedMemorySize, S2);
    (void)hipFuncSetAttribute((const void*)gru_pass<128, false, false>,
                              hipFuncAttributeMaxDynamicSharedMemorySize, S1);
    (void)hipFuncSetAttribute((const void*)gru_pass<1024, true, false>,
                              hipFuncAttributeMaxDynamicSharedMemorySize, S2);

    cvt_x_kernel<<<(T_DIM * B_DIM * I_PAD) / 256, 256, 0, stream>>>(x, x_bf);
    auto cvt = [&](const float* in, bf16* out, int kin, int kp) {
        long total = 3072L * kp;
        cvt_pad<<<(int)((total + 255) / 256), 256, 0, stream>>>(in, out, kin, kp, total);
    };
    cvt(e_Wih0, wih0e, 118, 128);
    cvt(e_Whh0, whh0e, 1024, 1024);
    cvt(e_Wih1, wih1e, 1024, 1024);
    cvt(e_Whh1, whh1e, 1024, 1024);
    cvt(d_Wih0, wih0d, 118, 128);
    cvt(d_Whh0, whh0d, 1024, 1024);
    cvt(d_Wih1, wih1d, 1024, 1024);
    cvt(d_Whh1, whh1d, 1024, 1024);

    // reset exchange state every launch (deterministic across graph replays)
    hipMemsetAsync(ex1, 0, 2ull * EX_SLOT * 4, stream);   // slot0 = tag-0 zeros
    hipMemsetAsync(ex2, 0, 2ull * EX_SLOT * 4, stream);
    hipMemsetAsync(fl1, 0, 4096, stream);
    hipMemsetAsync(fl2, 0, 4096, stream);

    // encoder layer 1: tagged recurrence; archive h1(t) -> h1all slot t+1
    gru_pass<128, false, true><<<256, 256, S1, stream>>>(
        x_bf, (long)B_DIM * I_PAD, wih0e, whh0e, e_bih0, e_bhh0,
        ex1, nullptr, h1all + HB, 1024, nullptr, hf1f, T_DIM, fl1);

    // encoder layer 2: tagged recurrence; x input = h1 archive (slot t+1)
    gru_pass<1024, true, true><<<256, 256, S2, stream>>>(
        h1all + HB, (long)HB, wih1e, whh1e, e_bih1, e_bhh1,
        ex2, nullptr, h2arc, 2, nullptr, hf2f, T_DIM, fl2);
    // final h2: bf16 in h2arc slot (511%2)=1, f32 in hf2f

    // decoder cell 1: x = x[:,511,:], h = h1(512) (archive slot 512 / hf1f)
    gru_pass<128, false, false><<<256, 256, S1, stream>>>(
        x_bf + 511L * B_DIM * I_PAD, 0, wih0d, whh0d, d_bih0, d_bhh0,
        nullptr, h1all + 512L * HB, hd1b, 1, hf1f, hd1f, 1, nullptr);

    // decoder cell 2: x = hd1, h = h2 (h2arc slot 1 / hf2f)
    gru_pass<1024, true, false><<<256, 256, S2, stream>>>(
        hd1b, 0, wih1d, whh1d, d_bih1, d_bhh1,
        nullptr, h2arc + HB, nullptr, 1, hf2f, hd2f, 1, nullptr);

    head_kernel<<<1, 1024, 0, stream>>>(hd2f, fc_W, fc_b, out_W, out_b,
                                        (float*)d_out);
}

// Round 6
// 5052.564 us; speedup vs baseline: 2.0067x; 2.0067x over previous
//
#include <hip/hip_runtime.h>
#include <hip/hip_bf16.h>

#define H_DIM 1024
#define B_DIM 64
#define T_DIM 512
#define I_PAD 128
#define I_ORIG 118
#define FC_DIM 16
#define HB (B_DIM * H_DIM)

typedef __hip_bfloat16 bf16;
typedef __attribute__((ext_vector_type(8))) short short8v;
typedef __attribute__((ext_vector_type(4))) float f32x4;

#define MFMA16(a, b, c) __builtin_amdgcn_mfma_f32_16x16x32_bf16(a, b, c, 0, 0, 0)

__device__ __forceinline__ short8v ldg8(const bf16* p) {
    return *reinterpret_cast<const short8v*>(p);
}
// 16B load bypassing L1/L2 (fresh from coherence point)
__device__ __forceinline__ short8v ld_byp16(const bf16* p) {
    union { unsigned long long u[2]; short8v v; } r;
    const unsigned long long* q = reinterpret_cast<const unsigned long long*>(p);
    r.u[0] = __hip_atomic_load(q,     __ATOMIC_RELAXED, __HIP_MEMORY_SCOPE_AGENT);
    r.u[1] = __hip_atomic_load(q + 1, __ATOMIC_RELAXED, __HIP_MEMORY_SCOPE_AGENT);
    return r.v;
}
__device__ __forceinline__ unsigned short f2bf_bits(float f) {
    union { bf16 h; unsigned short s; } u;
    u.h = __float2bfloat16(f);
    return u.s;
}
__device__ __forceinline__ unsigned ld_coh(const unsigned* p) {
    return __hip_atomic_load(p, __ATOMIC_RELAXED, __HIP_MEMORY_SCOPE_AGENT);
}
__device__ __forceinline__ void st_coh(unsigned* p, unsigned v) {
    __hip_atomic_store(p, v, __ATOMIC_RELAXED, __HIP_MEMORY_SCOPE_AGENT);
}

// ---------------------------------------------------------------------------
// x[b][t][i] f32 -> x_bf[t][b][c] bf16 (c padded 118->128 with zeros)
// ---------------------------------------------------------------------------
__global__ __launch_bounds__(256) void cvt_x_kernel(
    const float* __restrict__ x, bf16* __restrict__ out)
{
    int idx  = blockIdx.x * 256 + threadIdx.x;
    int c    = idx & 127;
    int rest = idx >> 7;
    int b    = rest & 63;
    int t    = rest >> 6;
    float v  = (c < I_ORIG) ? x[((long)b * T_DIM + t) * I_ORIG + c] : 0.0f;
    out[idx] = __float2bfloat16(v);
}

__global__ __launch_bounds__(256) void cvt_pad(
    const float* __restrict__ in, bf16* __restrict__ out,
    int kin, int kp, long total)
{
    long idx = (long)blockIdx.x * 256 + threadIdx.x;
    if (idx >= total) return;
    int  c = (int)(idx % kp);
    long r = idx / kp;
    out[idx] = __float2bfloat16(c < kin ? in[r * kin + c] : 0.0f);
}

// ---------------------------------------------------------------------------
// Persistent GRU pass. grid 256 x 256 (4 waves).
// bn = bid&63 (j-tile of 16), grp = bid>>6 (batch tile of 16 rows; the 4
// groups are independent recurrences).
// Sync protocol (per step):
//   producer wave: combine -> pair-packed sc1 h store -> s_waitcnt vmcnt(0)
//     -> lane0 relaxed sc1 store flags[grp][bn*4+w] = t+1   (distinct dword,
//     no RMW, no block sync needed: flags are per-wave granular)
//   consumer wave w: polls exactly its 64 producer flags (blocks 16w..16w+15
//     x 4 waves = 64 consecutive dwords, lane l polls one) with s_sleep(1)
//     throttle; releases independently of other waves.
// Data path: SEQ (pass 1) = write-once slots, sc1 stores + CACHED loads.
//   !SEQ (pass 2) = 2-slot ping-pong, sc1 stores + sc1-bypass loads.
//   Overwrite-safe: step-t writes happen only after poll confirmed all group
//   blocks completed step t-1. One __syncthreads/step (sm_red double-buffered).
// ---------------------------------------------------------------------------
template<int WXK, bool WXG, bool SEQ>
__global__ __launch_bounds__(256, 1) void gru_pass(
    const bf16* __restrict__ xbase, long xstride,
    const bf16* __restrict__ WxG,   // [3*1024][WXK] (staged to LDS if !WXG)
    const bf16* __restrict__ WhG,   // [3*1024][1024]
    const float* __restrict__ bih, const float* __restrict__ bhh,
    const bf16* hin,                // SEQ: slot array (read slot t); !SEQ: ping-pong[2*HB]
    bf16* hout,                     // SEQ: out base (write hout + t*HB); !SEQ: unused
    const float* f_init, float* f_final,
    int nsteps, unsigned* flags)
{
    extern __shared__ char smem[];
    constexpr int WH_BYTES = 3 * 16 * 1024 * 2;                  // 98304
    constexpr int WX_BYTES = WXG ? 0 : 3 * 16 * WXK * 2;
    float* sm_red = (float*)(smem + WH_BYTES + WX_BYTES);       // 2 x 4608 words

    const int tid  = threadIdx.x;
    const int w    = tid >> 6;
    const int lane = tid & 63;
    const int ln   = lane & 15;
    const int lk   = lane >> 4;
    const int bid  = blockIdx.x;
    const int bn   = bid & 63;
    const int grp  = bid >> 6;
    const int j0   = bn * 16;
    const int m0   = grp * 16;
    const int j    = j0 + ln;

    // ---- stage Whh into LDS (swizzled), rows of 2048B
    for (int c = tid; c < WH_BYTES / 16; c += 256) {
        int lin = c * 16;
        int row = lin >> 11;
        int wb  = lin & 2047;
        int g   = row >> 4, jj = row & 15;
        const bf16* src = WhG + ((long)(g * 1024 + j0 + jj) << 10) + (wb >> 1);
        *reinterpret_cast<short8v*>(smem + (lin ^ ((jj & 7) << 4))) = ldg8(src);
    }
    if constexpr (!WXG) {
        for (int c = tid; c < WX_BYTES / 16; c += 256) {
            int lin = c * 16;
            int row = lin / (WXK * 2);
            int wb  = lin % (WXK * 2);
            int g   = row >> 4, jj = row & 15;
            const bf16* src = WxG + (long)(g * 1024 + j0 + jj) * WXK + (wb >> 1);
            *reinterpret_cast<short8v*>(smem + WH_BYTES + (lin ^ ((jj & 7) << 4))) = ldg8(src);
        }
    }
    __syncthreads();

    const int wkoh = w << 8;
    const int wkox = (WXK == 128) ? (w << 5) : (w << 8);
    const int swz  = (ln & 7) << 4;
    const int whb0 = ln * 2048 + ((wkoh + lk * 8) << 1);

    const float bias_r  = bih[j] + bhh[j];
    const float bias_z  = bih[j + H_DIM] + bhh[j + H_DIM];
    const float bias_ni = bih[j + 2 * H_DIM];
    const float bias_nh = bhh[j + 2 * H_DIM];

    const int  crow = (w << 2) | lk;          // lane's output row offset
    const int  gm   = m0 + crow;
    const long opos = (long)gm * H_DIM + j;

    float hprev = f_init ? f_init[opos] : 0.0f;

    // flag addresses: producer (grp,bn,w) -> flags[grp*256 + bn*4 + w];
    // consumer wave w lane l -> flags[grp*256 + 64*w + l]
    unsigned* myflag = flags ? flags + (grp << 8) + (bn << 2) + w : nullptr;
    const unsigned* pollp = flags ? flags + (grp << 8) + (w << 6) + lane : nullptr;

    constexpr int NKX = (WXK == 128) ? 1 : 8;
    short8v xcur[NKX];
    {
        const bf16* xr = xbase + (long)(m0 + ln) * WXK + wkox + lk * 8;
#pragma unroll
        for (int ks = 0; ks < NKX; ++ks) xcur[ks] = ldg8(xr + ks * 32);
    }

    for (int t = 0; t < nsteps; ++t) {
        f32x4 aR{0,0,0,0}, aZ{0,0,0,0}, aNI{0,0,0,0}, aNH{0,0,0,0};

        // ---- input-side gates (independent of h(t-1)) — before the poll
        if constexpr (WXK == 128) {
            int o = WH_BYTES + ln * 256 + ((wkox + lk * 8) << 1);
            short8v br  = *(const short8v*)(smem + ((o       ) ^ swz));
            short8v bz  = *(const short8v*)(smem + ((o + 4096) ^ swz));
            short8v bnn = *(const short8v*)(smem + ((o + 8192) ^ swz));
            aR  = MFMA16(xcur[0], br,  aR);
            aZ  = MFMA16(xcur[0], bz,  aZ);
            aNI = MFMA16(xcur[0], bnn, aNI);
        } else {
            const bf16* wxr = WxG + (long)(j0 + ln) * 1024 + wkox + lk * 8;
#pragma unroll
            for (int ks = 0; ks < 8; ++ks) {
                short8v br  = ldg8(wxr + ks * 32);
                short8v bz  = ldg8(wxr + (1 << 20) + ks * 32);
                short8v bnn = ldg8(wxr + (2 << 20) + ks * 32);
                aR  = MFMA16(xcur[ks], br,  aR);
                aZ  = MFMA16(xcur[ks], bz,  aZ);
                aNI = MFMA16(xcur[ks], bnn, aNI);
            }
        }

        // ---- wait for this wave's 64 producer flags (k-quarter), throttled
        if (flags && t > 0) {
            const unsigned tgt = (unsigned)t;
            while (true) {
                unsigned fv = ld_coh(pollp);
                if (__all((int)(fv >= tgt))) break;
                __builtin_amdgcn_s_sleep(1);
            }
            asm volatile("" ::: "memory");
        }

        // ---- hidden-side A fragments (critical path: issue first)
        const bf16* bf_in = SEQ ? hin + (long)t * HB : hin + (long)(t & 1) * HB;
        const bf16* ha = bf_in + (long)(m0 + ln) * H_DIM + wkoh + lk * 8;
        short8v ah[8];
#pragma unroll
        for (int ks = 0; ks < 8; ++ks)
            ah[ks] = SEQ ? ldg8(ha + ks * 32) : ld_byp16(ha + ks * 32);

        // prefetch next step's x fragments (off the critical path)
        short8v xnext[NKX];
        if (t + 1 < nsteps) {
            const bf16* xr = xbase + (long)(t + 1) * xstride
                             + (long)(m0 + ln) * WXK + wkox + lk * 8;
#pragma unroll
            for (int ks = 0; ks < NKX; ++ks) xnext[ks] = ldg8(xr + ks * 32);
        }

        // ---- hidden-side MFMA (Whh from LDS)
#pragma unroll
        for (int ks = 0; ks < 8; ++ks) {
            int o = whb0 + ks * 64;
            short8v br  = *(const short8v*)(smem + ((o        ) ^ swz));
            short8v bz  = *(const short8v*)(smem + ((o + 32768) ^ swz));
            short8v bnn = *(const short8v*)(smem + ((o + 65536) ^ swz));
            aR  = MFMA16(ah[ks], br,  aR);
            aZ  = MFMA16(ah[ks], bz,  aZ);
            aNH = MFMA16(ah[ks], bnn, aNH);
        }

        // ---- K-split partials to LDS (18-word padded rows, double-buffered)
        float* red = sm_red + (t & 1) * 4608;
#pragma unroll
        for (int a = 0; a < 4; ++a) {
            f32x4 v = (a == 0) ? aR : (a == 1) ? aZ : (a == 2) ? aNI : aNH;
            int base = ((w << 2) + a) * 288 + (lk * 4) * 18 + ln;
#pragma unroll
            for (int e = 0; e < 4; ++e)
                red[base + e * 18] = v[e];
        }
        __syncthreads();   // the only per-step block barrier

        // ---- reduce across waves + combine (lane owns (gm, j))
        float sR = 0, sZ = 0, sNI = 0, sNH = 0;
#pragma unroll
        for (int w2 = 0; w2 < 4; ++w2) {
            int tb = (w2 << 2) * 288 + crow * 18 + ln;
            sR  += red[tb];
            sZ  += red[tb + 288];
            sNI += red[tb + 576];
            sNH += red[tb + 864];
        }
        float rr = 1.0f / (1.0f + __expf(-(sR + bias_r)));
        float zz = 1.0f / (1.0f + __expf(-(sZ + bias_z)));
        float xn = (sNI + bias_ni) + rr * (sNH + bias_nh);
        float nn = 2.0f / (1.0f + __expf(-2.0f * xn)) - 1.0f;
        float hv = (1.0f - zz) * nn + zz * hprev;
        hprev = hv;                                   // register-carried master

        // ---- h store (pair-packed bf16, sc1 -> coherence point)
        {
            bf16* wr = SEQ ? hout + (long)t * HB
                           : const_cast<bf16*>(hin) + (long)((t + 1) & 1) * HB;
            float ho = __shfl_xor(hv, 1);
            if ((ln & 1) == 0) {
                unsigned pk = (unsigned)f2bf_bits(hv)
                            | ((unsigned)f2bf_bits(ho) << 16);
                st_coh((unsigned*)(wr + (opos & ~1L)), pk);
            }
        }
        if (t == nsteps - 1 && f_final) f_final[opos] = hv;

        // ---- per-wave arrival flag (after this wave's stores are acked)
        if (flags && t + 1 < nsteps) {
            asm volatile("s_waitcnt vmcnt(0)" ::: "memory");
            if (lane == 0) st_coh(myflag, (unsigned)(t + 1));
        }

        if (t + 1 < nsteps) {
#pragma unroll
            for (int ks = 0; ks < NKX; ++ks) xcur[ks] = xnext[ks];
        }
    }
}

// ---------------------------------------------------------------------------
__global__ __launch_bounds__(1024) void head_kernel(
    const float* __restrict__ h2,
    const float* __restrict__ fc_W, const float* __restrict__ fc_b,
    const float* __restrict__ out_W, const float* __restrict__ out_b,
    float* __restrict__ y)
{
    __shared__ float acc_s[FC_DIM][B_DIM];
    const int b = threadIdx.x & 63;
    const int f = threadIdx.x >> 6;
    const float* wp = fc_W + (long)f * H_DIM;
    const float* hp = h2 + (long)b * H_DIM;
    float a = fc_b[f];
#pragma unroll 8
    for (int k = 0; k < H_DIM; ++k)
        a = fmaf(hp[k], wp[k], a);
    a = fmaxf(a, 0.0f);
    acc_s[f][b] = a * out_W[f];
    __syncthreads();
    if (threadIdx.x < 64) {
        float s = out_b[0];
#pragma unroll
        for (int f2 = 0; f2 < FC_DIM; ++f2) s += acc_s[f2][b];
        y[b] = s;
    }
}

// ---------------------------------------------------------------------------
extern "C" void kernel_launch(void* const* d_in, const int* in_sizes, int n_in,
                              void* d_out, int out_size, void* d_ws, size_t ws_size,
                              hipStream_t stream)
{
    const float* x      = (const float*)d_in[0];
    const float* e_Wih0 = (const float*)d_in[1];
    const float* e_Whh0 = (const float*)d_in[2];
    const float* e_bih0 = (const float*)d_in[3];
    const float* e_bhh0 = (const float*)d_in[4];
    const float* e_Wih1 = (const float*)d_in[5];
    const float* e_Whh1 = (const float*)d_in[6];
    const float* e_bih1 = (const float*)d_in[7];
    const float* e_bhh1 = (const float*)d_in[8];
    const float* d_Wih0 = (const float*)d_in[9];
    const float* d_Whh0 = (const float*)d_in[10];
    const float* d_bih0 = (const float*)d_in[11];
    const float* d_bhh0 = (const float*)d_in[12];
    const float* d_Wih1 = (const float*)d_in[13];
    const float* d_Whh1 = (const float*)d_in[14];
    const float* d_bih1 = (const float*)d_in[15];
    const float* d_bhh1 = (const float*)d_in[16];
    const float* fc_W   = (const float*)d_in[17];
    const float* fc_b   = (const float*)d_in[18];
    const float* out_W  = (const float*)d_in[19];
    const float* out_b  = (const float*)d_in[20];
    (void)in_sizes; (void)n_in; (void)out_size; (void)ws_size;

    char* p = (char*)d_ws;
    auto alloc = [&](size_t bytes) -> char* {
        char* r = p; p += (bytes + 255) & ~(size_t)255; return r;
    };
    bf16*  x_bf  = (bf16*)alloc((size_t)T_DIM * B_DIM * I_PAD * 2);
    bf16*  wih0e = (bf16*)alloc(3072ull * 128 * 2);
    bf16*  whh0e = (bf16*)alloc(3072ull * 1024 * 2);
    bf16*  wih1e = (bf16*)alloc(3072ull * 1024 * 2);
    bf16*  whh1e = (bf16*)alloc(3072ull * 1024 * 2);
    bf16*  wih0d = (bf16*)alloc(3072ull * 128 * 2);
    bf16*  whh0d = (bf16*)alloc(3072ull * 1024 * 2);
    bf16*  wih1d = (bf16*)alloc(3072ull * 1024 * 2);
    bf16*  whh1d = (bf16*)alloc(3072ull * 1024 * 2);
    bf16*  h1all = (bf16*)alloc(513ull * HB * 2);   // slot s = h1 after s steps
    bf16*  h2pp  = (bf16*)alloc(2ull * HB * 2);     // pass-2 ping-pong
    bf16*  hd1b  = (bf16*)alloc((size_t)HB * 2);
    bf16*  hd2b  = (bf16*)alloc((size_t)HB * 2);
    float* hf1f  = (float*)alloc((size_t)HB * 4);   // pass-1 final f32 h
    float* hf2f  = (float*)alloc((size_t)HB * 4);   // pass-2 final f32 h
    float* hd1f  = (float*)alloc((size_t)HB * 4);
    float* hd2f  = (float*)alloc((size_t)HB * 4);
    unsigned* fl1 = (unsigned*)alloc(4096);         // 4 grp x 64 bn x 4 w
    unsigned* fl2 = (unsigned*)alloc(4096);

    constexpr int RED = 2 * 4608 * 4;               // 36864
    constexpr int S1  = 98304 + 12288 + RED;        // 147456
    constexpr int S2  = 98304 + RED;                // 135168
    (void)hipFuncSetAttribute((const void*)gru_pass<128, false, true>,
                              hipFuncAttributeMaxDynamicSharedMemorySize, S1);
    (void)hipFuncSetAttribute((const void*)gru_pass<1024, true, false>,
                              hipFuncAttributeMaxDynamicSharedMemorySize, S2);
    (void)hipFuncSetAttribute((const void*)gru_pass<1024, true, true>,
                              hipFuncAttributeMaxDynamicSharedMemorySize, S2);

    cvt_x_kernel<<<(T_DIM * B_DIM * I_PAD) / 256, 256, 0, stream>>>(x, x_bf);
    auto cvt = [&](const float* in, bf16* out, int kin, int kp) {
        long total = 3072L * kp;
        cvt_pad<<<(int)((total + 255) / 256), 256, 0, stream>>>(in, out, kin, kp, total);
    };
    cvt(e_Wih0, wih0e, 118, 128);
    cvt(e_Whh0, whh0e, 1024, 1024);
    cvt(e_Wih1, wih1e, 1024, 1024);
    cvt(e_Whh1, whh1e, 1024, 1024);
    cvt(d_Wih0, wih0d, 118, 128);
    cvt(d_Whh0, whh0d, 1024, 1024);
    cvt(d_Wih1, wih1d, 1024, 1024);
    cvt(d_Whh1, whh1d, 1024, 1024);

    // reset recurrent state every launch (deterministic across graph replays)
    hipMemsetAsync(h1all, 0, (size_t)HB * 2, stream);   // h1 slot 0 = zeros
    hipMemsetAsync(h2pp,  0, 2ull * HB * 2, stream);    // h2 ping-pong = zeros
    hipMemsetAsync(fl1,   0, 4096, stream);
    hipMemsetAsync(fl2,   0, 4096, stream);

    // encoder layer 1 (SEQ): read slot t, write slot t+1 (hout = h1all+HB)
    gru_pass<128, false, true><<<256, 256, S1, stream>>>(
        x_bf, (long)B_DIM * I_PAD, wih0e, whh0e, e_bih0, e_bhh0,
        h1all, h1all + HB, nullptr, hf1f, T_DIM, fl1);

    // encoder layer 2 (!SEQ ping-pong): x input = h1(t) = slot t+1
    gru_pass<1024, true, false><<<256, 256, S2, stream>>>(
        h1all + HB, (long)HB, wih1e, whh1e, e_bih1, e_bhh1,
        h2pp, nullptr, nullptr, hf2f, T_DIM, fl2);
    // final h2(511) lands in ping-pong slot ((511+1)&1) = 0, f32 in hf2f

    // decoder cell 1: x = x[:,511,:], h = h1(512) (slot 512 / hf1f)
    gru_pass<128, false, true><<<256, 256, S1, stream>>>(
        x_bf + 511L * B_DIM * I_PAD, 0, wih0d, whh0d, d_bih0, d_bhh0,
        h1all + 512L * HB, hd1b, hf1f, hd1f, 1, nullptr);

    // decoder cell 2: x = hd1, h = h2 final (h2pp slot 0 / hf2f)
    gru_pass<1024, true, true><<<256, 256, S2, stream>>>(
        hd1b, 0, wih1d, whh1d, d_bih1, d_bhh1,
        h2pp, hd2b, hf2f, hd2f, 1, nullptr);

    head_kernel<<<1, 1024, 0, stream>>>(hd2f, fc_W, fc_b, out_W, out_b,
                                        (float*)d_out);
}

// Round 7
// 4153.714 us; speedup vs baseline: 2.4409x; 1.2164x over previous
//
#include <hip/hip_runtime.h>
#include <hip/hip_bf16.h>

#define H_DIM 1024
#define B_DIM 64
#define T_DIM 512
#define I_PAD 128
#define I_ORIG 118
#define FC_DIM 16
#define HB (B_DIM * H_DIM)

typedef __hip_bfloat16 bf16;
typedef __attribute__((ext_vector_type(8))) short short8v;
typedef __attribute__((ext_vector_type(4))) float f32x4;

#define MFMA16(a, b, c) __builtin_amdgcn_mfma_f32_16x16x32_bf16(a, b, c, 0, 0, 0)

__device__ __forceinline__ short8v ldg8(const bf16* p) {
    return *reinterpret_cast<const short8v*>(p);
}
// 16B load bypassing L1/L2 (fresh from coherence point)
__device__ __forceinline__ short8v ld_byp16(const bf16* p) {
    union { unsigned long long u[2]; short8v v; } r;
    const unsigned long long* q = reinterpret_cast<const unsigned long long*>(p);
    r.u[0] = __hip_atomic_load(q,     __ATOMIC_RELAXED, __HIP_MEMORY_SCOPE_AGENT);
    r.u[1] = __hip_atomic_load(q + 1, __ATOMIC_RELAXED, __HIP_MEMORY_SCOPE_AGENT);
    return r.v;
}
__device__ __forceinline__ unsigned short f2bf_bits(float f) {
    union { bf16 h; unsigned short s; } u;
    u.h = __float2bfloat16(f);
    return u.s;
}
__device__ __forceinline__ unsigned ld_coh(const unsigned* p) {
    return __hip_atomic_load(p, __ATOMIC_RELAXED, __HIP_MEMORY_SCOPE_AGENT);
}
__device__ __forceinline__ void st_coh(unsigned* p, unsigned v) {
    __hip_atomic_store(p, v, __ATOMIC_RELAXED, __HIP_MEMORY_SCOPE_AGENT);
}

// ---------------------------------------------------------------------------
// x[b][t][i] f32 -> x_bf[t][b][c] bf16 (c padded 118->128 with zeros)
// ---------------------------------------------------------------------------
__global__ __launch_bounds__(256) void cvt_x_kernel(
    const float* __restrict__ x, bf16* __restrict__ out)
{
    int idx  = blockIdx.x * 256 + threadIdx.x;
    int c    = idx & 127;
    int rest = idx >> 7;
    int b    = rest & 63;
    int t    = rest >> 6;
    float v  = (c < I_ORIG) ? x[((long)b * T_DIM + t) * I_ORIG + c] : 0.0f;
    out[idx] = __float2bfloat16(v);
}

__global__ __launch_bounds__(256) void cvt_pad(
    const float* __restrict__ in, bf16* __restrict__ out,
    int kin, int kp, long total)
{
    long idx = (long)blockIdx.x * 256 + threadIdx.x;
    if (idx >= total) return;
    int  c = (int)(idx % kp);
    long r = idx / kp;
    out[idx] = __float2bfloat16(c < kin ? in[r * kin + c] : 0.0f);
}

// ---------------------------------------------------------------------------
// Persistent GRU pass. grid 256 x 256 (4 waves).
// bn = bid&63 (j-tile of 16), grp = bid>>6 (batch tile of 16 rows; the 4
// groups are independent recurrences).
// Per-step protocol (critical chain minimized):
//   pre-poll: input-side MFMAs (depend only on x / prev-pass data)
//   poll: wave w bare-spins on its 64 producer flags (1 dword/lane, sc1;
//         naturally throttled by MALL load latency)
//   release -> h-load (cached for write-once slots, sc1-bypass for ping-pong)
//   -> hidden MFMA -> LDS K-reduce (1 syncthreads, dbuf) -> combine
//   -> pair-packed sc1 h store -> s_waitcnt vmcnt(0)  [ONLY the store is
//      outstanding: prefetches were consumed, next prefetch issued later]
//   -> lane0 flag store -> issue next-step x prefetch (has the whole next
//      poll window to complete; cannot be hoisted above the "memory" asm)
// ---------------------------------------------------------------------------
template<int WXK, bool WXG, bool SEQ>
__global__ __launch_bounds__(256, 1) void gru_pass(
    const bf16* __restrict__ xbase, long xstride,
    const bf16* __restrict__ WxG,   // [3*1024][WXK] (staged to LDS if !WXG)
    const bf16* __restrict__ WhG,   // [3*1024][1024]
    const float* __restrict__ bih, const float* __restrict__ bhh,
    const bf16* hin,                // SEQ: slot array (read slot t); !SEQ: ping-pong[2*HB]
    bf16* hout,                     // SEQ: out base (write hout + t*HB); !SEQ: unused
    const float* f_init, float* f_final,
    int nsteps, unsigned* flags)
{
    extern __shared__ char smem[];
    constexpr int WH_BYTES = 3 * 16 * 1024 * 2;                  // 98304
    constexpr int WX_BYTES = WXG ? 0 : 3 * 16 * WXK * 2;
    float* sm_red = (float*)(smem + WH_BYTES + WX_BYTES);       // 2 x 4608 words

    const int tid  = threadIdx.x;
    const int w    = tid >> 6;
    const int lane = tid & 63;
    const int ln   = lane & 15;
    const int lk   = lane >> 4;
    const int bid  = blockIdx.x;
    const int bn   = bid & 63;
    const int grp  = bid >> 6;
    const int j0   = bn * 16;
    const int m0   = grp * 16;
    const int j    = j0 + ln;

    // ---- stage Whh into LDS (swizzled), rows of 2048B
    for (int c = tid; c < WH_BYTES / 16; c += 256) {
        int lin = c * 16;
        int row = lin >> 11;
        int wb  = lin & 2047;
        int g   = row >> 4, jj = row & 15;
        const bf16* src = WhG + ((long)(g * 1024 + j0 + jj) << 10) + (wb >> 1);
        *reinterpret_cast<short8v*>(smem + (lin ^ ((jj & 7) << 4))) = ldg8(src);
    }
    if constexpr (!WXG) {
        for (int c = tid; c < WX_BYTES / 16; c += 256) {
            int lin = c * 16;
            int row = lin / (WXK * 2);
            int wb  = lin % (WXK * 2);
            int g   = row >> 4, jj = row & 15;
            const bf16* src = WxG + (long)(g * 1024 + j0 + jj) * WXK + (wb >> 1);
            *reinterpret_cast<short8v*>(smem + WH_BYTES + (lin ^ ((jj & 7) << 4))) = ldg8(src);
        }
    }
    __syncthreads();

    const int wkoh = w << 8;
    const int wkox = (WXK == 128) ? (w << 5) : (w << 8);
    const int swz  = (ln & 7) << 4;
    const int whb0 = ln * 2048 + ((wkoh + lk * 8) << 1);

    const float bias_r  = bih[j] + bhh[j];
    const float bias_z  = bih[j + H_DIM] + bhh[j + H_DIM];
    const float bias_ni = bih[j + 2 * H_DIM];
    const float bias_nh = bhh[j + 2 * H_DIM];

    const int  crow = (w << 2) | lk;          // lane's output row offset
    const int  gm   = m0 + crow;
    const long opos = (long)gm * H_DIM + j;

    float hprev = f_init ? f_init[opos] : 0.0f;

    // flag addresses: producer (grp,bn,w) -> flags[grp*256 + bn*4 + w];
    // consumer wave w lane l -> flags[grp*256 + 64*w + l]
    unsigned* myflag = flags ? flags + (grp << 8) + (bn << 2) + w : nullptr;
    const unsigned* pollp = flags ? flags + (grp << 8) + (w << 6) + lane : nullptr;

    constexpr int NKX = (WXK == 128) ? 1 : 8;
    short8v xcur[NKX];
    {
        const bf16* xr = xbase + (long)(m0 + ln) * WXK + wkox + lk * 8;
#pragma unroll
        for (int ks = 0; ks < NKX; ++ks) xcur[ks] = ldg8(xr + ks * 32);
    }

    for (int t = 0; t < nsteps; ++t) {
        f32x4 aR{0,0,0,0}, aZ{0,0,0,0}, aNI{0,0,0,0}, aNH{0,0,0,0};

        // ---- input-side gates (independent of h(t-1)) — before the poll
        if constexpr (WXK == 128) {
            int o = WH_BYTES + ln * 256 + ((wkox + lk * 8) << 1);
            short8v br  = *(const short8v*)(smem + ((o       ) ^ swz));
            short8v bz  = *(const short8v*)(smem + ((o + 4096) ^ swz));
            short8v bnn = *(const short8v*)(smem + ((o + 8192) ^ swz));
            aR  = MFMA16(xcur[0], br,  aR);
            aZ  = MFMA16(xcur[0], bz,  aZ);
            aNI = MFMA16(xcur[0], bnn, aNI);
        } else {
            const bf16* wxr = WxG + (long)(j0 + ln) * 1024 + wkox + lk * 8;
#pragma unroll
            for (int ks = 0; ks < 8; ++ks) {
                short8v br  = ldg8(wxr + ks * 32);
                short8v bz  = ldg8(wxr + (1 << 20) + ks * 32);
                short8v bnn = ldg8(wxr + (2 << 20) + ks * 32);
                aR  = MFMA16(xcur[ks], br,  aR);
                aZ  = MFMA16(xcur[ks], bz,  aZ);
                aNI = MFMA16(xcur[ks], bnn, aNI);
            }
        }

        // ---- bare-spin on this wave's 64 producer flags (k-quarter)
        if (flags && t > 0) {
            const unsigned tgt = (unsigned)t;
            while (true) {
                unsigned fv = ld_coh(pollp);
                if (__all((int)(fv >= tgt))) break;
            }
            asm volatile("" ::: "memory");
        }

        // ---- hidden-side A fragments (critical path: issue first)
        const bf16* bf_in = SEQ ? hin + (long)t * HB : hin + (long)(t & 1) * HB;
        const bf16* ha = bf_in + (long)(m0 + ln) * H_DIM + wkoh + lk * 8;
        short8v ah[8];
#pragma unroll
        for (int ks = 0; ks < 8; ++ks)
            ah[ks] = SEQ ? ldg8(ha + ks * 32) : ld_byp16(ha + ks * 32);

        // ---- hidden-side MFMA (Whh from LDS)
#pragma unroll
        for (int ks = 0; ks < 8; ++ks) {
            int o = whb0 + ks * 64;
            short8v br  = *(const short8v*)(smem + ((o        ) ^ swz));
            short8v bz  = *(const short8v*)(smem + ((o + 32768) ^ swz));
            short8v bnn = *(const short8v*)(smem + ((o + 65536) ^ swz));
            aR  = MFMA16(ah[ks], br,  aR);
            aZ  = MFMA16(ah[ks], bz,  aZ);
            aNH = MFMA16(ah[ks], bnn, aNH);
        }

        // ---- K-split partials to LDS (18-word padded rows, double-buffered)
        float* red = sm_red + (t & 1) * 4608;
#pragma unroll
        for (int a = 0; a < 4; ++a) {
            f32x4 v = (a == 0) ? aR : (a == 1) ? aZ : (a == 2) ? aNI : aNH;
            int base = ((w << 2) + a) * 288 + (lk * 4) * 18 + ln;
#pragma unroll
            for (int e = 0; e < 4; ++e)
                red[base + e * 18] = v[e];
        }
        __syncthreads();   // the only per-step block barrier

        // ---- reduce across waves + combine (lane owns (gm, j))
        float sR = 0, sZ = 0, sNI = 0, sNH = 0;
#pragma unroll
        for (int w2 = 0; w2 < 4; ++w2) {
            int tb = (w2 << 2) * 288 + crow * 18 + ln;
            sR  += red[tb];
            sZ  += red[tb + 288];
            sNI += red[tb + 576];
            sNH += red[tb + 864];
        }
        float rr = 1.0f / (1.0f + __expf(-(sR + bias_r)));
        float zz = 1.0f / (1.0f + __expf(-(sZ + bias_z)));
        float xn = (sNI + bias_ni) + rr * (sNH + bias_nh);
        float nn = 2.0f / (1.0f + __expf(-2.0f * xn)) - 1.0f;
        float hv = (1.0f - zz) * nn + zz * hprev;
        hprev = hv;                                   // register-carried master

        // ---- h store (pair-packed bf16, sc1 -> coherence point)
        {
            bf16* wr = SEQ ? hout + (long)t * HB
                           : const_cast<bf16*>(hin) + (long)((t + 1) & 1) * HB;
            float ho = __shfl_xor(hv, 1);
            if ((ln & 1) == 0) {
                unsigned pk = (unsigned)f2bf_bits(hv)
                            | ((unsigned)f2bf_bits(ho) << 16);
                st_coh((unsigned*)(wr + (opos & ~1L)), pk);
            }
        }

        // ---- ack ONLY the h store, then flag, then prefetch
        if (flags && t + 1 < nsteps) {
            asm volatile("s_waitcnt vmcnt(0)" ::: "memory");
            if (lane == 0) st_coh(myflag, (unsigned)(t + 1));
        }

        // ---- next-step x prefetch (post-flag: off the critical chain,
        //      completes during the next poll window)
        if (t + 1 < nsteps) {
            const bf16* xr = xbase + (long)(t + 1) * xstride
                             + (long)(m0 + ln) * WXK + wkox + lk * 8;
#pragma unroll
            for (int ks = 0; ks < NKX; ++ks) xcur[ks] = ldg8(xr + ks * 32);
        }

        if (t == nsteps - 1 && f_final) f_final[opos] = hv;
    }
}

// ---------------------------------------------------------------------------
__global__ __launch_bounds__(1024) void head_kernel(
    const float* __restrict__ h2,
    const float* __restrict__ fc_W, const float* __restrict__ fc_b,
    const float* __restrict__ out_W, const float* __restrict__ out_b,
    float* __restrict__ y)
{
    __shared__ float acc_s[FC_DIM][B_DIM];
    const int b = threadIdx.x & 63;
    const int f = threadIdx.x >> 6;
    const float* wp = fc_W + (long)f * H_DIM;
    const float* hp = h2 + (long)b * H_DIM;
    float a = fc_b[f];
#pragma unroll 8
    for (int k = 0; k < H_DIM; ++k)
        a = fmaf(hp[k], wp[k], a);
    a = fmaxf(a, 0.0f);
    acc_s[f][b] = a * out_W[f];
    __syncthreads();
    if (threadIdx.x < 64) {
        float s = out_b[0];
#pragma unroll
        for (int f2 = 0; f2 < FC_DIM; ++f2) s += acc_s[f2][b];
        y[b] = s;
    }
}

// ---------------------------------------------------------------------------
extern "C" void kernel_launch(void* const* d_in, const int* in_sizes, int n_in,
                              void* d_out, int out_size, void* d_ws, size_t ws_size,
                              hipStream_t stream)
{
    const float* x      = (const float*)d_in[0];
    const float* e_Wih0 = (const float*)d_in[1];
    const float* e_Whh0 = (const float*)d_in[2];
    const float* e_bih0 = (const float*)d_in[3];
    const float* e_bhh0 = (const float*)d_in[4];
    const float* e_Wih1 = (const float*)d_in[5];
    const float* e_Whh1 = (const float*)d_in[6];
    const float* e_bih1 = (const float*)d_in[7];
    const float* e_bhh1 = (const float*)d_in[8];
    const float* d_Wih0 = (const float*)d_in[9];
    const float* d_Whh0 = (const float*)d_in[10];
    const float* d_bih0 = (const float*)d_in[11];
    const float* d_bhh0 = (const float*)d_in[12];
    const float* d_Wih1 = (const float*)d_in[13];
    const float* d_Whh1 = (const float*)d_in[14];
    const float* d_bih1 = (const float*)d_in[15];
    const float* d_bhh1 = (const float*)d_in[16];
    const float* fc_W   = (const float*)d_in[17];
    const float* fc_b   = (const float*)d_in[18];
    const float* out_W  = (const float*)d_in[19];
    const float* out_b  = (const float*)d_in[20];
    (void)in_sizes; (void)n_in; (void)out_size; (void)ws_size;

    char* p = (char*)d_ws;
    auto alloc = [&](size_t bytes) -> char* {
        char* r = p; p += (bytes + 255) & ~(size_t)255; return r;
    };
    bf16*  x_bf  = (bf16*)alloc((size_t)T_DIM * B_DIM * I_PAD * 2);
    bf16*  wih0e = (bf16*)alloc(3072ull * 128 * 2);
    bf16*  whh0e = (bf16*)alloc(3072ull * 1024 * 2);
    bf16*  wih1e = (bf16*)alloc(3072ull * 1024 * 2);
    bf16*  whh1e = (bf16*)alloc(3072ull * 1024 * 2);
    bf16*  wih0d = (bf16*)alloc(3072ull * 128 * 2);
    bf16*  whh0d = (bf16*)alloc(3072ull * 1024 * 2);
    bf16*  wih1d = (bf16*)alloc(3072ull * 1024 * 2);
    bf16*  whh1d = (bf16*)alloc(3072ull * 1024 * 2);
    bf16*  h1all = (bf16*)alloc(513ull * HB * 2);   // slot s = h1 after s steps
    bf16*  h2pp  = (bf16*)alloc(2ull * HB * 2);     // pass-2 ping-pong
    bf16*  hd1b  = (bf16*)alloc((size_t)HB * 2);
    bf16*  hd2b  = (bf16*)alloc((size_t)HB * 2);
    float* hf1f  = (float*)alloc((size_t)HB * 4);   // pass-1 final f32 h
    float* hf2f  = (float*)alloc((size_t)HB * 4);   // pass-2 final f32 h
    float* hd1f  = (float*)alloc((size_t)HB * 4);
    float* hd2f  = (float*)alloc((size_t)HB * 4);
    unsigned* fl1 = (unsigned*)alloc(4096);         // 4 grp x 64 bn x 4 w
    unsigned* fl2 = (unsigned*)alloc(4096);

    constexpr int RED = 2 * 4608 * 4;               // 36864
    constexpr int S1  = 98304 + 12288 + RED;        // 147456
    constexpr int S2  = 98304 + RED;                // 135168
    (void)hipFuncSetAttribute((const void*)gru_pass<128, false, true>,
                              hipFuncAttributeMaxDynamicSharedMemorySize, S1);
    (void)hipFuncSetAttribute((const void*)gru_pass<1024, true, false>,
                              hipFuncAttributeMaxDynamicSharedMemorySize, S2);
    (void)hipFuncSetAttribute((const void*)gru_pass<1024, true, true>,
                              hipFuncAttributeMaxDynamicSharedMemorySize, S2);

    cvt_x_kernel<<<(T_DIM * B_DIM * I_PAD) / 256, 256, 0, stream>>>(x, x_bf);
    auto cvt = [&](const float* in, bf16* out, int kin, int kp) {
        long total = 3072L * kp;
        cvt_pad<<<(int)((total + 255) / 256), 256, 0, stream>>>(in, out, kin, kp, total);
    };
    cvt(e_Wih0, wih0e, 118, 128);
    cvt(e_Whh0, whh0e, 1024, 1024);
    cvt(e_Wih1, wih1e, 1024, 1024);
    cvt(e_Whh1, whh1e, 1024, 1024);
    cvt(d_Wih0, wih0d, 118, 128);
    cvt(d_Whh0, whh0d, 1024, 1024);
    cvt(d_Wih1, wih1d, 1024, 1024);
    cvt(d_Whh1, whh1d, 1024, 1024);

    // reset recurrent state every launch (deterministic across graph replays)
    hipMemsetAsync(h1all, 0, (size_t)HB * 2, stream);   // h1 slot 0 = zeros
    hipMemsetAsync(h2pp,  0, 2ull * HB * 2, stream);    // h2 ping-pong = zeros
    hipMemsetAsync(fl1,   0, 4096, stream);
    hipMemsetAsync(fl2,   0, 4096, stream);

    // encoder layer 1 (SEQ): read slot t, write slot t+1 (hout = h1all+HB)
    gru_pass<128, false, true><<<256, 256, S1, stream>>>(
        x_bf, (long)B_DIM * I_PAD, wih0e, whh0e, e_bih0, e_bhh0,
        h1all, h1all + HB, nullptr, hf1f, T_DIM, fl1);

    // encoder layer 2 (!SEQ ping-pong): x input = h1(t) = slot t+1
    gru_pass<1024, true, false><<<256, 256, S2, stream>>>(
        h1all + HB, (long)HB, wih1e, whh1e, e_bih1, e_bhh1,
        h2pp, nullptr, nullptr, hf2f, T_DIM, fl2);
    // final h2(511) lands in ping-pong slot ((511+1)&1) = 0, f32 in hf2f

    // decoder cell 1: x = x[:,511,:], h = h1(512) (slot 512 / hf1f)
    gru_pass<128, false, true><<<256, 256, S1, stream>>>(
        x_bf + 511L * B_DIM * I_PAD, 0, wih0d, whh0d, d_bih0, d_bhh0,
        h1all + 512L * HB, hd1b, hf1f, hd1f, 1, nullptr);

    // decoder cell 2: x = hd1, h = h2 final (h2pp slot 0 / hf2f)
    gru_pass<1024, true, true><<<256, 256, S2, stream>>>(
        hd1b, 0, wih1d, whh1d, d_bih1, d_bhh1,
        h2pp, hd2b, hf2f, hd2f, 1, nullptr);

    head_kernel<<<1, 1024, 0, stream>>>(hd2f, fc_W, fc_b, out_W, out_b,
                                        (float*)d_out);
}